// Round 13
// baseline (1041.467 us; speedup 1.0000x reference)
//
#include <hip/hip_runtime.h>
#include <hip/hip_bf16.h>
#include <math.h>

typedef short bf16x8 __attribute__((ext_vector_type(8)));
typedef float f32x4 __attribute__((ext_vector_type(4)));
typedef __hip_bfloat16 bf16;

#define NEGV -1e10f
#define LOGEPS -9.210340371976182f  // log(1e-4)
#define HL2PI 0.9189385332046727f   // 0.5*log(2*pi)
#define SENT 0xFFFFFFFFFFFFFFFFULL

__device__ __forceinline__ f32x4 mfma16(bf16x8 a, bf16x8 b, f32x4 c) {
  return __builtin_amdgcn_mfma_f32_16x16x32_bf16(a, b, c, 0, 0, 0);
}
__device__ __forceinline__ bf16x8 ld8(const bf16* p) { return *(const bf16x8*)(const void*)p; }
__device__ __forceinline__ bf16 f2b(float v) { return __float2bfloat16(v); }
__device__ __forceinline__ float sh2f(short s) {
  unsigned u = ((unsigned)(unsigned short)s) << 16; float f; __builtin_memcpy(&f, &u, 4); return f;
}
__device__ __forceinline__ short f2sh(float v) {
  bf16 b = f2b(v); short s; __builtin_memcpy(&s, &b, 2); return s;
}
__device__ __forceinline__ float fsigm(float x) { return 1.f / (1.f + __expf(-x)); }
__device__ __forceinline__ float ftanh(float x) { return 1.f - 2.f / (1.f + __expf(2.f * x)); }
// volatile (sc0, L1-bypass) accessors: L2-coherent within one XCD
__device__ __forceinline__ unsigned long long VL64(const unsigned long long* p) {
  return *(const volatile unsigned long long*)p;
}
__device__ __forceinline__ void VS64(unsigned long long* p, unsigned long long v) {
  *(volatile unsigned long long*)p = v;
}

// ---------------------------------------------------------------- prep
__global__ void k_prep(const float* __restrict__ inputs, const float* __restrict__ mels,
                       const float* __restrict__ pw0, const float* __restrict__ pw1,
                       const float* __restrict__ wih, const float* __restrict__ whh,
                       const float* __restrict__ bih, const float* __restrict__ bhh,
                       const float* __restrict__ ow0, const float* __restrict__ ow1,
                       const float* __restrict__ ow2, const float* __restrict__ ob2,
                       bf16* ib, bf16* ar, bf16* w0p, bf16* w1b, bf16* wihb, bf16* whhb,
                       float* bias2, bf16* ow0Eb, bf16* ow0Mb, bf16* ow1b, bf16* ow2pb,
                       float* ob2p, unsigned long long* hg, int* ctl) {
  int t0 = blockIdx.x * blockDim.x + threadIdx.x;
  int nt = gridDim.x * blockDim.x;
  for (int i = t0; i < 256 * 1024; i += nt) hg[i] = SENT;  // data-poll sentinels (scan only)
  for (int i = t0; i < 16; i += nt) ctl[i] = (i == 8) ? -1 : 0;  // [0..7]=per-XCD cnt, [8]=winner
  for (int i = t0; i < 8*128*512; i += nt) ib[i] = f2b(inputs[i]);
  for (int i = t0; i < 2048*96; i += nt) {
    int r = i / 96, d = i - r * 96; int t = r >> 3, b = r & 7;
    float v = (d < 80 && t > 0) ? mels[((size_t)b*80 + d)*256 + (t-1)] : 0.f;
    ar[i] = f2b(v);
  }
  for (int i = t0; i < 256*96; i += nt) {
    int j = i / 96, d = i - j * 96;
    w0p[i] = f2b(d < 80 ? pw0[j*80 + d] : 0.f);
  }
  for (int i = t0; i < 256*256; i += nt) w1b[i] = f2b(pw1[i]);
  for (int i = t0; i < 2048*256; i += nt) wihb[i] = f2b(wih[i]);
  for (int i = t0; i < 2048*512; i += nt) whhb[i] = f2b(whh[i]);
  for (int i = t0; i < 2048; i += nt) bias2[i] = bih[i] + bhh[i];
  for (int i = t0; i < 256*512; i += nt) {
    int j = i >> 9, k = i & 511;
    ow0Eb[i] = f2b(ow0[(size_t)j*1024 + k]);
    ow0Mb[i] = f2b(ow0[(size_t)j*1024 + 512 + k]);
  }
  for (int i = t0; i < 256*256; i += nt) ow1b[i] = f2b(ow1[i]);
  for (int i = t0; i < 176*256; i += nt) {
    int r = i >> 8;
    ow2pb[i] = f2b(r < 161 ? ow2[i] : 0.f);
  }
  for (int i = t0; i < 176; i += nt) ob2p[i] = (i < 161) ? ob2[i] : 0.f;
}

// ---------------------------------------------------------------- generic MFMA GEMM (head + hterm)
__global__ __launch_bounds__(256) void k_gemm(const bf16* __restrict__ A, const bf16* __restrict__ W,
                                              const float* __restrict__ bias, void* __restrict__ Cout,
                                              int M, int N, int K, int flags) {
  int wave = threadIdx.x >> 6, lane = threadIdx.x & 63;
  int l16 = lane & 15, quad = lane >> 4;
  int row0 = blockIdx.y * 64 + wave * 16;
  int col0 = blockIdx.x * 64;
  const bf16* arow = A + (size_t)(row0 + l16) * K + quad * 8;
  f32x4 acc[4] = {};
  for (int kt = 0; kt < K; kt += 32) {
    bf16x8 af = ld8(arow + kt);
#pragma unroll
    for (int nt = 0; nt < 4; nt++) {
      bf16x8 wf = ld8(W + (size_t)(col0 + nt*16 + l16) * K + kt + quad * 8);
      acc[nt] = mfma16(af, wf, acc[nt]);
    }
  }
#pragma unroll
  for (int nt = 0; nt < 4; nt++) {
    int col = col0 + nt * 16 + l16;
    float bv = bias ? bias[col] : 0.f;
#pragma unroll
    for (int r = 0; r < 4; r++) {
      int row = row0 + quad * 4 + r;
      float v = acc[nt][r] + bv;
      if (flags & 1) v = v > 0.f ? v : 0.f;
      if (flags & 2) ((bf16*)Cout)[(size_t)row * N + col] = f2b(v);
      else ((float*)Cout)[(size_t)row * N + col] = v;
    }
  }
}

// ---------------------------------------------------------------- LSTM scan, XCD-pinned (v6)
// 256 launched blocks; each reads HW_REG_XCC_ID; per-XCD slot claim, first XCD
// to fill 16 slots wins; its 16 blocks (co-resident on one XCD's 32 CUs) run the
// R4 engine with VOLATILE (sc0) L2 loads/stores instead of agent (MALL) atomics:
// the shared per-XCD L2 is the coherence point, RT ~200cy vs ~800cy at the MALL.
// Correctness scope-safe: each hg word written once; a stale read can only show
// the sentinel (retry). Cross-kernel visibility via kernel-end L2 flush.
__global__ __launch_bounds__(512, 1) void k_lstm(const float* __restrict__ gx,
                                                 const bf16* __restrict__ whhb,
                                                 unsigned long long* __restrict__ hg,
                                                 int* __restrict__ ctl) {
  __shared__ __align__(16) bf16 hb[2][64 * 16 * 8];
  __shared__ int s_slot;
  const int tid = threadIdx.x;
  if (tid == 0) {
    unsigned xcc;
    asm volatile("s_getreg_b32 %0, hwreg(HW_REG_XCC_ID)" : "=s"(xcc));
    xcc &= 7;
    int idx = __hip_atomic_fetch_add(ctl + xcc, 1, __ATOMIC_RELAXED, __HIP_MEMORY_SCOPE_AGENT);
    int slot = -1;
    if (idx < 16) {
      if (idx == 15) {
        int expected = -1;
        __hip_atomic_compare_exchange_strong(ctl + 8, &expected, (int)xcc,
                                             __ATOMIC_RELAXED, __ATOMIC_RELAXED,
                                             __HIP_MEMORY_SCOPE_AGENT);
      }
      int w;
      while ((w = __hip_atomic_load(ctl + 8, __ATOMIC_RELAXED, __HIP_MEMORY_SCOPE_AGENT)) == -1)
        __builtin_amdgcn_s_sleep(2);
      if (w == (int)xcc) slot = idx;
    }
    s_slot = slot;
  }
  __syncthreads();
  const int q = s_slot;
  if (q < 0) return;  // not a worker
  const int wave = tid >> 6, lane = tid & 63, l16 = lane & 15, quad = lane >> 4;
  const int jrow = (l16 & 3) * 512 + q * 32 + wave * 4 + (l16 >> 2);
  bf16x8 Af[16];
#pragma unroll
  for (int c = 0; c < 16; c++) Af[c] = ld8(whhb + (size_t)jrow * 512 + c * 32 + quad * 8);
  {
    bf16 z = f2b(0.f);
    bf16* hp = &hb[0][0];
    for (int i = tid; i < 2 * 64 * 16 * 8; i += 512) hp[i] = z;
  }
  const int b_ep = l16 & 7;
  const int gx_col = q * 32 + wave * 4 + quad;
  const int w0i = tid, w1i = tid + 512;
  const int o0 = (((w0i & 127) >> 1) * 16 + (w0i >> 7)) * 8 + ((w0i & 1) << 2);
  const int o1 = (((w1i & 127) >> 1) * 16 + (w1i >> 7)) * 8 + ((w1i & 1) << 2);
  const int hword = b_ep * 128 + q * 8 + wave;
  float cst = 0.f;
  const float* gp0 = gx + (size_t)b_ep * 2048 + gx_col;
  float gx0 = gp0[0], gx1 = gp0[512], gx2 = gp0[1024], gx3 = gp0[1536];
  for (int t = 0; t < 256; t++) {
    int buf = t & 1;
    if (t > 0) {
      const unsigned long long* src = hg + (size_t)(t - 1) * 1024;
      unsigned long long v0 = VL64(src + w0i);
      unsigned long long v1 = VL64(src + w1i);
      int tries = 0;
      while (v0 == SENT || v1 == SENT) {
        if (++tries > 32) __builtin_amdgcn_s_sleep(1);
        if (v0 == SENT) v0 = VL64(src + w0i);
        if (v1 == SENT) v1 = VL64(src + w1i);
      }
      *(unsigned long long*)&hb[buf][o0] = v0;
      *(unsigned long long*)&hb[buf][o1] = v1;
    }
    __syncthreads();
    int tn = (t + 1) & 255;
    const float* gpn = gx + ((size_t)tn * 8 + b_ep) * 2048 + gx_col;
    float n0 = gpn[0], n1 = gpn[512], n2 = gpn[1024], n3 = gpn[1536];
    f32x4 a0 = {}, a1 = {}, a2 = {}, a3 = {};
#pragma unroll
    for (int c = 0; c < 16; c += 4) {
      a0 = mfma16(Af[c + 0], ld8(&hb[buf][(((c + 0) * 4 + quad) * 16 + l16) * 8]), a0);
      a1 = mfma16(Af[c + 1], ld8(&hb[buf][(((c + 1) * 4 + quad) * 16 + l16) * 8]), a1);
      a2 = mfma16(Af[c + 2], ld8(&hb[buf][(((c + 2) * 4 + quad) * 16 + l16) * 8]), a2);
      a3 = mfma16(Af[c + 3], ld8(&hb[buf][(((c + 3) * 4 + quad) * 16 + l16) * 8]), a3);
    }
    f32x4 acc = (a0 + a1) + (a2 + a3);
    float gi = acc[0] + gx0, gf = acc[1] + gx1, gg = acc[2] + gx2, go = acc[3] + gx3;
    cst = fsigm(gf) * cst + fsigm(gi) * ftanh(gg);
    float h = fsigm(go) * ftanh(cst);
    unsigned hu = (unsigned short)f2sh(h);
    unsigned h1 = __shfl_xor((int)hu, 16);
    unsigned h2 = __shfl_xor((int)hu, 32);
    unsigned h3 = __shfl_xor((int)h1, 32);
    if (quad == 0 && l16 < 8) {
      unsigned long long w64 = (unsigned long long)hu | ((unsigned long long)h1 << 16) |
                               ((unsigned long long)h2 << 32) | ((unsigned long long)h3 << 48);
      VS64(hg + (size_t)t * 1024 + hword, w64);
    }
    gx0 = n0; gx1 = n1; gx2 = n2; gx3 = n3;
  }
}

// ---------------------------------------------------------------- output net + emission v3
// One block per (t,b): 2048 blocks x 512 thr, 2 blocks/CU (LDS ~69.6KB).
#define LDA1 264
__global__ __launch_bounds__(512, 1) void k_out3(
    const float* __restrict__ hterm, const bf16* __restrict__ baseb,
    const bf16* __restrict__ w1, const bf16* __restrict__ w2,
    const float* __restrict__ ob1, const float* __restrict__ ob2p,
    const float* __restrict__ mels, const int* __restrict__ ilen,
    float* __restrict__ em, float* __restrict__ tv) {
  __shared__ __align__(16) bf16 a_buf[128 * LDA1];
  __shared__ float ht[256];
  __shared__ float xt[80];
  __shared__ float ob2s[176];
  const int tb = blockIdx.x, t = tb >> 3, b = tb & 7;
  const int tid = threadIdx.x;
  const int wave = tid >> 6, lane = tid & 63, l16 = lane & 15, quad = lane >> 4;
  if (tid < 256) ht[tid] = hterm[(size_t)tb * 256 + tid];
  if (tid < 80) xt[tid] = mels[((size_t)b * 80 + tid) * 256 + t];
  if (tid >= 256 && tid < 432) ob2s[tid - 256] = ob2p[tid - 256];
  __syncthreads();
  const bf16* bb = baseb + (size_t)b * 128 * 256;
  {
    int r0 = tid >> 5, c0 = (tid & 31) * 8;
    float hv[8];
#pragma unroll
    for (int j = 0; j < 8; j++) hv[j] = ht[c0 + j];
    for (int i = r0; i < 128; i += 16) {
      bf16x8 bv = ld8(bb + i * 256 + c0);
      bf16x8 ov;
#pragma unroll
      for (int j = 0; j < 8; j++) {
        float v = sh2f(bv[j]) + hv[j];
        ov[j] = f2sh(v > 0.f ? v : 0.f);
      }
      *(bf16x8*)&a_buf[i * LDA1 + c0] = ov;
    }
  }
  __syncthreads();
  f32x4 accB[8][2] = {};
  for (int kt = 0; kt < 256; kt += 32) {
    bf16x8 wf[2];
#pragma unroll
    for (int nt = 0; nt < 2; nt++)
      wf[nt] = ld8(w1 + (size_t)(wave * 32 + nt * 16 + l16) * 256 + kt + quad * 8);
#pragma unroll
    for (int mt = 0; mt < 8; mt++) {
      bf16x8 afr = ld8(a_buf + (mt * 16 + l16) * LDA1 + kt + quad * 8);
#pragma unroll
      for (int nt = 0; nt < 2; nt++) accB[mt][nt] = mfma16(afr, wf[nt], accB[mt][nt]);
    }
  }
  __syncthreads();
#pragma unroll
  for (int nt = 0; nt < 2; nt++) {
    int col = wave * 32 + nt * 16 + l16;
    float bv = ob1[col];
#pragma unroll
    for (int mt = 0; mt < 8; mt++)
#pragma unroll
      for (int r = 0; r < 4; r++) {
        int row = mt * 16 + quad * 4 + r;
        float v = accB[mt][nt][r] + bv;
        a_buf[row * LDA1 + col] = f2b(v > 0.f ? v : 0.f);
      }
  }
  __syncthreads();
  f32x4 accC[11] = {};
  for (int kt = 0; kt < 256; kt += 32) {
    bf16x8 af0 = ld8(a_buf + (wave * 16 + l16) * LDA1 + kt + quad * 8);
#pragma unroll
    for (int nt = 0; nt < 11; nt++) {
      bf16x8 wf = ld8(w2 + (size_t)(nt * 16 + l16) * 256 + kt + quad * 8);
      accC[nt] = mfma16(af0, wf, accC[nt]);
    }
  }
  int my_len = ilen[b];
  float xd[5];
#pragma unroll
  for (int qq = 0; qq < 5; qq++) xd[qq] = xt[qq * 16 + l16];
#pragma unroll
  for (int r = 0; r < 4; r++) {
    int row = wave * 16 + quad * 4 + r;
    float pv[11];
#pragma unroll
    for (int nt = 0; nt < 11; nt++) pv[nt] = accC[nt][r] + ob2s[nt * 16 + l16];
    float s = 0.f;
#pragma unroll
    for (int qq = 0; qq < 5; qq++) {
      float mean = pv[qq], sh = pv[qq + 5];
      float sp = fmaxf(sh, 0.f) + __logf(1.f + __expf(-fabsf(sh)));
      float sd = sp + 0.001f;
      float z = (xd[qq] - mean) / sd;
      s += -0.5f * z * z - __logf(sd);
    }
    s += __shfl_xor(s, 1); s += __shfl_xor(s, 2);
    s += __shfl_xor(s, 4); s += __shfl_xor(s, 8);
    float emv = (row < my_len) ? (s - 80.f * HL2PI) : 0.f;
    if (l16 == 0) {
      size_t oidx = (size_t)tb * 128 + row;
      em[oidx] = emv;
      tv[oidx] = pv[10];
    }
  }
}

// ---------------------------------------------------------------- HMM forward (8 blocks, 1 wave each)
__global__ __launch_bounds__(64) void k_hmm(const float* __restrict__ em, const float* __restrict__ tv,
                                            const int* __restrict__ ilen, const int* __restrict__ mlen,
                                            float* __restrict__ out) {
  int b = blockIdx.x, lane = threadIdx.x;
  int len = ilen[b], ml = mlen[b];
  bool m0 = lane < len, m1 = (64 + lane) < len;
  float la0 = 0.f, la1 = 0.f, lp = 0.f;
  size_t base = (size_t)b * 128 + lane;
  float e0n = em[base], e1n = em[base + 64];
  float v0n = tv[base], v1n = tv[base + 64];
  for (int t = 0; t < 256; t++) {
    float e0 = e0n, e1 = e1n, v0 = v0n, v1 = v1n;
    if (t < 255) {
      size_t idx = base + (size_t)(t + 1) * 1024;
      e0n = em[idx]; e1n = em[idx + 64];
      v0n = tv[idx]; v1n = tv[idx + 64];
    }
    if (t == 0) {
      la0 = (lane == 0 ? 0.f : NEGV) + e0;
      la1 = NEGV + e1;
    } else {
      float L0 = __logf(1.f + __expf(-fabsf(v0))), L1 = __logf(1.f + __expf(-fabsf(v1)));
      float ls0 = fmaxf(-(fmaxf(v0, 0.f) + L0), LOGEPS);
      float lm0 = fmaxf(-(fmaxf(-v0, 0.f) + L0), LOGEPS);
      float ls1 = fmaxf(-(fmaxf(v1, 0.f) + L1), LOGEPS);
      float lm1 = fmaxf(-(fmaxf(-v1, 0.f) + L1), LOGEPS);
      float stay0 = la0 + ls0, stay1 = la1 + ls1;
      float mv0 = la0 + lm0, mv1 = la1 + lm1;
      float pm0 = __shfl_up(mv0, 1);
      float pm1 = __shfl_up(mv1, 1);
      float mv0_63 = __shfl(mv0, 63);
      float le0 = (lane == 0) ? NEGV : pm0;
      float le1 = (lane == 0) ? mv0_63 : pm1;
      float mxa = fmaxf(stay0, le0), mna = fminf(stay0, le0);
      float o0 = mxa + __logf(1.f + __expf(mna - mxa));
      float mxb = fmaxf(stay1, le1), mnb = fminf(stay1, le1);
      float o1 = mxb + __logf(1.f + __expf(mnb - mxb));
      o0 = m0 ? o0 : NEGV; o1 = m1 ? o1 : NEGV;
      la0 = e0 + o0; la1 = e1 + o1;
    }
    float mx = fmaxf(la0, la1);
#pragma unroll
    for (int s = 1; s < 64; s <<= 1) mx = fmaxf(mx, __shfl_xor(mx, s));
    float sm = __expf(la0 - mx) + __expf(la1 - mx);
#pragma unroll
    for (int s = 1; s < 64; s <<= 1) sm += __shfl_xor(sm, s);
    float lc = mx + __logf(sm);
    la0 -= lc; la1 -= lc;
    size_t o = 8 + ((size_t)b * 256 + t) * 128 + lane;
    out[o] = la0;
    out[o + 64] = la1;
    if (t < ml) lp += lc;
  }
  if (lane == 0) out[b] = lp;
}

// ---------------------------------------------------------------- launch
extern "C" void kernel_launch(void* const* d_in, const int* in_sizes, int n_in,
                              void* d_out, int out_size, void* d_ws, size_t ws_size,
                              hipStream_t stream) {
  const float* inputs = (const float*)d_in[0];
  const float* mels   = (const float*)d_in[1];
  const float* pw0    = (const float*)d_in[2];
  const float* pw1    = (const float*)d_in[3];
  const float* wih    = (const float*)d_in[4];
  const float* whh    = (const float*)d_in[5];
  const float* bih    = (const float*)d_in[6];
  const float* bhh    = (const float*)d_in[7];
  const float* ow0    = (const float*)d_in[8];
  const float* ob0    = (const float*)d_in[9];
  const float* ow1    = (const float*)d_in[10];
  const float* ob1    = (const float*)d_in[11];
  const float* ow2    = (const float*)d_in[12];
  const float* ob2    = (const float*)d_in[13];
  const int* ilen     = (const int*)d_in[14];
  const int* mlen     = (const int*)d_in[15];
  float* out = (float*)d_out;

  char* w = (char*)d_ws;
  size_t off = 0;
  auto carve = [&](size_t bytes) -> char* {
    char* p = w + off;
    off = (off + bytes + 255) & ~(size_t)255;
    return p;
  };
  bf16*  ib     = (bf16*)carve(8*128*512 * 2);
  bf16*  ar     = (bf16*)carve(2048*96 * 2);
  bf16*  w0p    = (bf16*)carve(256*96 * 2);
  bf16*  w1b    = (bf16*)carve(256*256 * 2);
  bf16*  wihb   = (bf16*)carve(2048*256 * 2);
  bf16*  whhb   = (bf16*)carve((size_t)2048*512 * 2);
  float* bias2  = (float*)carve(2048 * 4);
  bf16*  ow0Eb  = (bf16*)carve(256*512 * 2);
  bf16*  ow0Mb  = (bf16*)carve(256*512 * 2);
  bf16*  ow1b   = (bf16*)carve(256*256 * 2);
  bf16*  ow2pb  = (bf16*)carve(176*256 * 2);
  float* ob2p   = (float*)carve(176 * 4);
  bf16*  pre1   = (bf16*)carve(2048*256 * 2);
  bf16*  pre2   = (bf16*)carve(2048*256 * 2);
  float* gx     = (float*)carve((size_t)2048*2048 * 4);
  bf16*  baseb  = (bf16*)carve(1024*256 * 2);
  unsigned long long* hg = (unsigned long long*)carve((size_t)256 * 1024 * 8);
  float* hterm  = (float*)carve((size_t)2048*256 * 4);
  float* emb    = (float*)carve((size_t)2048*128 * 4);
  float* tvb    = (float*)carve((size_t)2048*128 * 4);
  int*   ctl    = (int*)carve(64);

  k_prep<<<512, 256, 0, stream>>>(inputs, mels, pw0, pw1, wih, whh, bih, bhh, ow0, ow1, ow2, ob2,
                                  ib, ar, w0p, w1b, wihb, whhb, bias2, ow0Eb, ow0Mb, ow1b, ow2pb,
                                  ob2p, hg, ctl);
  k_gemm<<<dim3(4, 32), 256, 0, stream>>>(ar, w0p, nullptr, pre1, 2048, 256, 96, 1 | 2);
  k_gemm<<<dim3(4, 32), 256, 0, stream>>>(pre1, w1b, nullptr, pre2, 2048, 256, 256, 1 | 2);
  k_gemm<<<dim3(32, 32), 256, 0, stream>>>(pre2, wihb, bias2, gx, 2048, 2048, 256, 0);
  k_gemm<<<dim3(4, 16), 256, 0, stream>>>(ib, ow0Eb, ob0, baseb, 1024, 256, 512, 2);
  k_lstm<<<256, 512, 0, stream>>>(gx, whhb, hg, ctl);
  k_gemm<<<dim3(4, 32), 256, 0, stream>>>((const bf16*)hg, ow0Mb, nullptr, hterm, 2048, 256, 512, 0);
  k_out3<<<2048, 512, 0, stream>>>(hterm, baseb, ow1b, ow2pb, ob1, ob2p, mels, ilen, emb, tvb);
  k_hmm<<<8, 64, 0, stream>>>(emb, tvb, ilen, mlen, out);
}

// Round 14
// 929.271 us; speedup vs baseline: 1.1207x; 1.1207x over previous
//
#include <hip/hip_runtime.h>
#include <hip/hip_bf16.h>
#include <math.h>

typedef short bf16x8 __attribute__((ext_vector_type(8)));
typedef float f32x4 __attribute__((ext_vector_type(4)));
typedef __hip_bfloat16 bf16;

#define NEGV -1e10f
#define LOGEPS -9.210340371976182f  // log(1e-4)
#define HL2PI 0.9189385332046727f   // 0.5*log(2*pi)
#define SENT 0xFFFFFFFFFFFFFFFFULL

__device__ __forceinline__ f32x4 mfma16(bf16x8 a, bf16x8 b, f32x4 c) {
  return __builtin_amdgcn_mfma_f32_16x16x32_bf16(a, b, c, 0, 0, 0);
}
__device__ __forceinline__ bf16x8 ld8(const bf16* p) { return *(const bf16x8*)(const void*)p; }
__device__ __forceinline__ bf16 f2b(float v) { return __float2bfloat16(v); }
__device__ __forceinline__ float sh2f(short s) {
  unsigned u = ((unsigned)(unsigned short)s) << 16; float f; __builtin_memcpy(&f, &u, 4); return f;
}
__device__ __forceinline__ short f2sh(float v) {
  bf16 b = f2b(v); short s; __builtin_memcpy(&s, &b, 2); return s;
}
__device__ __forceinline__ float fsigm(float x) { return 1.f / (1.f + __expf(-x)); }
__device__ __forceinline__ float ftanh(float x) { return 1.f - 2.f / (1.f + __expf(2.f * x)); }
__device__ __forceinline__ unsigned long long AL64(const unsigned long long* p) {
  return __hip_atomic_load(p, __ATOMIC_RELAXED, __HIP_MEMORY_SCOPE_AGENT);
}
__device__ __forceinline__ void AS64(unsigned long long* p, unsigned long long v) {
  __hip_atomic_store(p, v, __ATOMIC_RELAXED, __HIP_MEMORY_SCOPE_AGENT);
}

// ---------------------------------------------------------------- prep
__global__ void k_prep(const float* __restrict__ inputs, const float* __restrict__ mels,
                       const float* __restrict__ pw0, const float* __restrict__ pw1,
                       const float* __restrict__ wih, const float* __restrict__ whh,
                       const float* __restrict__ bih, const float* __restrict__ bhh,
                       const float* __restrict__ ow0, const float* __restrict__ ow1,
                       const float* __restrict__ ow2, const float* __restrict__ ob2,
                       bf16* ib, bf16* ar, bf16* w0p, bf16* w1b, bf16* wihb, bf16* whhb,
                       float* bias2, bf16* ow0Eb, bf16* ow0Mb, bf16* ow1b, bf16* ow2pb,
                       float* ob2p, unsigned long long* hg) {
  int t0 = blockIdx.x * blockDim.x + threadIdx.x;
  int nt = gridDim.x * blockDim.x;
  for (int i = t0; i < 256 * 1024; i += nt) hg[i] = SENT;  // data-poll sentinels (scan only)
  for (int i = t0; i < 8*128*512; i += nt) ib[i] = f2b(inputs[i]);
  for (int i = t0; i < 2048*96; i += nt) {
    int r = i / 96, d = i - r * 96; int t = r >> 3, b = r & 7;
    float v = (d < 80 && t > 0) ? mels[((size_t)b*80 + d)*256 + (t-1)] : 0.f;
    ar[i] = f2b(v);
  }
  for (int i = t0; i < 256*96; i += nt) {
    int j = i / 96, d = i - j * 96;
    w0p[i] = f2b(d < 80 ? pw0[j*80 + d] : 0.f);
  }
  for (int i = t0; i < 256*256; i += nt) w1b[i] = f2b(pw1[i]);
  for (int i = t0; i < 2048*256; i += nt) wihb[i] = f2b(wih[i]);
  for (int i = t0; i < 2048*512; i += nt) whhb[i] = f2b(whh[i]);
  for (int i = t0; i < 2048; i += nt) bias2[i] = bih[i] + bhh[i];
  for (int i = t0; i < 256*512; i += nt) {
    int j = i >> 9, k = i & 511;
    ow0Eb[i] = f2b(ow0[(size_t)j*1024 + k]);
    ow0Mb[i] = f2b(ow0[(size_t)j*1024 + 512 + k]);
  }
  for (int i = t0; i < 256*256; i += nt) ow1b[i] = f2b(ow1[i]);
  for (int i = t0; i < 176*256; i += nt) {
    int r = i >> 8;
    ow2pb[i] = f2b(r < 161 ? ow2[i] : 0.f);
  }
  for (int i = t0; i < 176; i += nt) ob2p[i] = (i < 161) ? ob2[i] : 0.f;
}

// ---------------------------------------------------------------- generic MFMA GEMM (head + hterm)
__global__ __launch_bounds__(256) void k_gemm(const bf16* __restrict__ A, const bf16* __restrict__ W,
                                              const float* __restrict__ bias, void* __restrict__ Cout,
                                              int M, int N, int K, int flags) {
  int wave = threadIdx.x >> 6, lane = threadIdx.x & 63;
  int l16 = lane & 15, quad = lane >> 4;
  int row0 = blockIdx.y * 64 + wave * 16;
  int col0 = blockIdx.x * 64;
  const bf16* arow = A + (size_t)(row0 + l16) * K + quad * 8;
  f32x4 acc[4] = {};
  for (int kt = 0; kt < K; kt += 32) {
    bf16x8 af = ld8(arow + kt);
#pragma unroll
    for (int nt = 0; nt < 4; nt++) {
      bf16x8 wf = ld8(W + (size_t)(col0 + nt*16 + l16) * K + kt + quad * 8);
      acc[nt] = mfma16(af, wf, acc[nt]);
    }
  }
#pragma unroll
  for (int nt = 0; nt < 4; nt++) {
    int col = col0 + nt * 16 + l16;
    float bv = bias ? bias[col] : 0.f;
#pragma unroll
    for (int r = 0; r < 4; r++) {
      int row = row0 + quad * 4 + r;
      float v = acc[nt][r] + bv;
      if (flags & 1) v = v > 0.f ? v : 0.f;
      if (flags & 2) ((bf16*)Cout)[(size_t)row * N + col] = f2b(v);
      else ((float*)Cout)[(size_t)row * N + col] = v;
    }
  }
}

// ---------------------------------------------------------------- LSTM scan (R12-proven: agent atomics + backoff)
// 16 blocks x 512 threads, idle-GPU scan (max clocks). Data-is-the-barrier:
// sentinel polls on MALL (relaxed agent atomics), parallel, 32-round tight then
// s_sleep(1) backoff; gx software-pipelined; fragment-order LDS; 4 independent
// MFMA chains; fast transcendentals. Stable at 428us (R11/R12, no outliers).
__global__ __launch_bounds__(512, 1) void k_lstm(const float* __restrict__ gx,
                                                 const bf16* __restrict__ whhb,
                                                 unsigned long long* __restrict__ hg) {
  __shared__ __align__(16) bf16 hb[2][64 * 16 * 8];
  const int tid = threadIdx.x, q = blockIdx.x;
  const int wave = tid >> 6, lane = tid & 63, l16 = lane & 15, quad = lane >> 4;
  const int jrow = (l16 & 3) * 512 + q * 32 + wave * 4 + (l16 >> 2);
  bf16x8 Af[16];
#pragma unroll
  for (int c = 0; c < 16; c++) Af[c] = ld8(whhb + (size_t)jrow * 512 + c * 32 + quad * 8);
  {
    bf16 z = f2b(0.f);
    bf16* hp = &hb[0][0];
    for (int i = tid; i < 2 * 64 * 16 * 8; i += 512) hp[i] = z;
  }
  const int b_ep = l16 & 7;
  const int gx_col = q * 32 + wave * 4 + quad;
  const int w0i = tid, w1i = tid + 512;
  const int o0 = (((w0i & 127) >> 1) * 16 + (w0i >> 7)) * 8 + ((w0i & 1) << 2);
  const int o1 = (((w1i & 127) >> 1) * 16 + (w1i >> 7)) * 8 + ((w1i & 1) << 2);
  const int hword = b_ep * 128 + q * 8 + wave;
  float cst = 0.f;
  const float* gp0 = gx + (size_t)b_ep * 2048 + gx_col;
  float gx0 = gp0[0], gx1 = gp0[512], gx2 = gp0[1024], gx3 = gp0[1536];
  for (int t = 0; t < 256; t++) {
    int buf = t & 1;
    if (t > 0) {
      const unsigned long long* src = hg + (size_t)(t - 1) * 1024;
      unsigned long long v0 = AL64(src + w0i);
      unsigned long long v1 = AL64(src + w1i);
      int tries = 0;
      while (v0 == SENT || v1 == SENT) {
        if (++tries > 32) __builtin_amdgcn_s_sleep(1);
        if (v0 == SENT) v0 = AL64(src + w0i);
        if (v1 == SENT) v1 = AL64(src + w1i);
      }
      *(unsigned long long*)&hb[buf][o0] = v0;
      *(unsigned long long*)&hb[buf][o1] = v1;
    }
    __syncthreads();
    int tn = (t + 1) & 255;
    const float* gpn = gx + ((size_t)tn * 8 + b_ep) * 2048 + gx_col;
    float n0 = gpn[0], n1 = gpn[512], n2 = gpn[1024], n3 = gpn[1536];
    f32x4 a0 = {}, a1 = {}, a2 = {}, a3 = {};
#pragma unroll
    for (int c = 0; c < 16; c += 4) {
      a0 = mfma16(Af[c + 0], ld8(&hb[buf][(((c + 0) * 4 + quad) * 16 + l16) * 8]), a0);
      a1 = mfma16(Af[c + 1], ld8(&hb[buf][(((c + 1) * 4 + quad) * 16 + l16) * 8]), a1);
      a2 = mfma16(Af[c + 2], ld8(&hb[buf][(((c + 2) * 4 + quad) * 16 + l16) * 8]), a2);
      a3 = mfma16(Af[c + 3], ld8(&hb[buf][(((c + 3) * 4 + quad) * 16 + l16) * 8]), a3);
    }
    f32x4 acc = (a0 + a1) + (a2 + a3);
    float gi = acc[0] + gx0, gf = acc[1] + gx1, gg = acc[2] + gx2, go = acc[3] + gx3;
    cst = fsigm(gf) * cst + fsigm(gi) * ftanh(gg);
    float h = fsigm(go) * ftanh(cst);
    unsigned hu = (unsigned short)f2sh(h);
    unsigned h1 = __shfl_xor((int)hu, 16);
    unsigned h2 = __shfl_xor((int)hu, 32);
    unsigned h3 = __shfl_xor((int)h1, 32);
    if (quad == 0 && l16 < 8) {
      unsigned long long w64 = (unsigned long long)hu | ((unsigned long long)h1 << 16) |
                               ((unsigned long long)h2 << 32) | ((unsigned long long)h3 << 48);
      AS64(hg + (size_t)t * 1024 + hword, w64);
    }
    gx0 = n0; gx1 = n1; gx2 = n2; gx3 = n3;
  }
}

// ---------------------------------------------------------------- output net + emission (R4-proven shape)
// One block per (t,b): 2048 blocks x 256 thr (the 927us-total config), 2 blocks/CU.
#define LDA1 264
__global__ __launch_bounds__(256, 2) void k_out(const bf16* __restrict__ base, const float* __restrict__ hterm,
                                                const bf16* __restrict__ w1, const bf16* __restrict__ w2,
                                                const float* __restrict__ ob1, const float* __restrict__ ob2p,
                                                const float* __restrict__ mels, const int* __restrict__ ilen,
                                                float* __restrict__ em, float* __restrict__ tv) {
  __shared__ __align__(16) bf16 a_buf[128 * LDA1];
  __shared__ float ht[256];
  __shared__ float xt[80];
  __shared__ float ob2s[176];
  int tb = blockIdx.x, t = tb >> 3, b = tb & 7;
  int tid = threadIdx.x;
  ht[tid] = hterm[(size_t)tb * 256 + tid];
  if (tid < 80) xt[tid] = mels[((size_t)b * 80 + tid) * 256 + t];
  if (tid < 176) ob2s[tid] = ob2p[tid];
  __syncthreads();
  const bf16* bb = base + (size_t)b * 128 * 256;
  {
    int r0 = tid >> 5, c0 = (tid & 31) * 8;
    float hv[8];
#pragma unroll
    for (int j = 0; j < 8; j++) hv[j] = ht[c0 + j];
    for (int i = r0; i < 128; i += 8) {
      bf16x8 bv = ld8(bb + i * 256 + c0);
      bf16x8 ov;
#pragma unroll
      for (int j = 0; j < 8; j++) {
        float v = sh2f(bv[j]) + hv[j];
        ov[j] = f2sh(v > 0.f ? v : 0.f);
      }
      *(bf16x8*)&a_buf[i * LDA1 + c0] = ov;
    }
  }
  __syncthreads();
  int wave = tid >> 6, lane = tid & 63, l16 = lane & 15, quad = lane >> 4;
  f32x4 accB[8][4] = {};
  for (int kt = 0; kt < 256; kt += 32) {
    bf16x8 wf[4];
#pragma unroll
    for (int nt = 0; nt < 4; nt++)
      wf[nt] = ld8(w1 + (size_t)(wave * 64 + nt * 16 + l16) * 256 + kt + quad * 8);
#pragma unroll
    for (int mt = 0; mt < 8; mt++) {
      bf16x8 af = ld8(a_buf + (mt * 16 + l16) * LDA1 + kt + quad * 8);
#pragma unroll
      for (int nt = 0; nt < 4; nt++) accB[mt][nt] = mfma16(af, wf[nt], accB[mt][nt]);
    }
  }
  __syncthreads();
#pragma unroll
  for (int nt = 0; nt < 4; nt++) {
    int col = wave * 64 + nt * 16 + l16;
    float bv = ob1[col];
#pragma unroll
    for (int mt = 0; mt < 8; mt++)
#pragma unroll
      for (int r = 0; r < 4; r++) {
        int row = mt * 16 + quad * 4 + r;
        float v = accB[mt][nt][r] + bv;
        a_buf[row * LDA1 + col] = f2b(v > 0.f ? v : 0.f);
      }
  }
  __syncthreads();
  f32x4 accC[2][11] = {};
  for (int kt = 0; kt < 256; kt += 32) {
    bf16x8 af0 = ld8(a_buf + ((wave * 2 + 0) * 16 + l16) * LDA1 + kt + quad * 8);
    bf16x8 af1 = ld8(a_buf + ((wave * 2 + 1) * 16 + l16) * LDA1 + kt + quad * 8);
#pragma unroll
    for (int nt = 0; nt < 11; nt++) {
      bf16x8 wf = ld8(w2 + (size_t)(nt * 16 + l16) * 256 + kt + quad * 8);
      accC[0][nt] = mfma16(af0, wf, accC[0][nt]);
      accC[1][nt] = mfma16(af1, wf, accC[1][nt]);
    }
  }
  int my_len = ilen[b];
  float xd[5];
#pragma unroll
  for (int qq = 0; qq < 5; qq++) xd[qq] = xt[qq * 16 + l16];
#pragma unroll
  for (int m2 = 0; m2 < 2; m2++)
#pragma unroll
    for (int r = 0; r < 4; r++) {
      int row = (wave * 2 + m2) * 16 + quad * 4 + r;
      float pv[11];
#pragma unroll
      for (int nt = 0; nt < 11; nt++) pv[nt] = accC[m2][nt][r] + ob2s[nt * 16 + l16];
      float s = 0.f;
#pragma unroll
      for (int qq = 0; qq < 5; qq++) {
        float mean = pv[qq], sh = pv[qq + 5];
        float sp = fmaxf(sh, 0.f) + __logf(1.f + __expf(-fabsf(sh)));
        float sd = sp + 0.001f;
        float z = (xd[qq] - mean) / sd;
        s += -0.5f * z * z - __logf(sd);
      }
      s += __shfl_xor(s, 1); s += __shfl_xor(s, 2);
      s += __shfl_xor(s, 4); s += __shfl_xor(s, 8);
      float emv = (row < my_len) ? (s - 80.f * HL2PI) : 0.f;
      if (l16 == 0) {
        em[(size_t)tb * 128 + row] = emv;
        tv[(size_t)tb * 128 + row] = pv[10];
      }
    }
}

// ---------------------------------------------------------------- HMM forward (8 blocks, 1 wave each)
__global__ __launch_bounds__(64) void k_hmm(const float* __restrict__ em, const float* __restrict__ tv,
                                            const int* __restrict__ ilen, const int* __restrict__ mlen,
                                            float* __restrict__ out) {
  int b = blockIdx.x, lane = threadIdx.x;
  int len = ilen[b], ml = mlen[b];
  bool m0 = lane < len, m1 = (64 + lane) < len;
  float la0 = 0.f, la1 = 0.f, lp = 0.f;
  size_t base = (size_t)b * 128 + lane;
  float e0n = em[base], e1n = em[base + 64];
  float v0n = tv[base], v1n = tv[base + 64];
  for (int t = 0; t < 256; t++) {
    float e0 = e0n, e1 = e1n, v0 = v0n, v1 = v1n;
    if (t < 255) {
      size_t idx = base + (size_t)(t + 1) * 1024;
      e0n = em[idx]; e1n = em[idx + 64];
      v0n = tv[idx]; v1n = tv[idx + 64];
    }
    if (t == 0) {
      la0 = (lane == 0 ? 0.f : NEGV) + e0;
      la1 = NEGV + e1;
    } else {
      float L0 = __logf(1.f + __expf(-fabsf(v0))), L1 = __logf(1.f + __expf(-fabsf(v1)));
      float ls0 = fmaxf(-(fmaxf(v0, 0.f) + L0), LOGEPS);
      float lm0 = fmaxf(-(fmaxf(-v0, 0.f) + L0), LOGEPS);
      float ls1 = fmaxf(-(fmaxf(v1, 0.f) + L1), LOGEPS);
      float lm1 = fmaxf(-(fmaxf(-v1, 0.f) + L1), LOGEPS);
      float stay0 = la0 + ls0, stay1 = la1 + ls1;
      float mv0 = la0 + lm0, mv1 = la1 + lm1;
      float pm0 = __shfl_up(mv0, 1);
      float pm1 = __shfl_up(mv1, 1);
      float mv0_63 = __shfl(mv0, 63);
      float le0 = (lane == 0) ? NEGV : pm0;
      float le1 = (lane == 0) ? mv0_63 : pm1;
      float mxa = fmaxf(stay0, le0), mna = fminf(stay0, le0);
      float o0 = mxa + __logf(1.f + __expf(mna - mxa));
      float mxb = fmaxf(stay1, le1), mnb = fminf(stay1, le1);
      float o1 = mxb + __logf(1.f + __expf(mnb - mxb));
      o0 = m0 ? o0 : NEGV; o1 = m1 ? o1 : NEGV;
      la0 = e0 + o0; la1 = e1 + o1;
    }
    float mx = fmaxf(la0, la1);
#pragma unroll
    for (int s = 1; s < 64; s <<= 1) mx = fmaxf(mx, __shfl_xor(mx, s));
    float sm = __expf(la0 - mx) + __expf(la1 - mx);
#pragma unroll
    for (int s = 1; s < 64; s <<= 1) sm += __shfl_xor(sm, s);
    float lc = mx + __logf(sm);
    la0 -= lc; la1 -= lc;
    size_t o = 8 + ((size_t)b * 256 + t) * 128 + lane;
    out[o] = la0;
    out[o + 64] = la1;
    if (t < ml) lp += lc;
  }
  if (lane == 0) out[b] = lp;
}

// ---------------------------------------------------------------- launch
extern "C" void kernel_launch(void* const* d_in, const int* in_sizes, int n_in,
                              void* d_out, int out_size, void* d_ws, size_t ws_size,
                              hipStream_t stream) {
  const float* inputs = (const float*)d_in[0];
  const float* mels   = (const float*)d_in[1];
  const float* pw0    = (const float*)d_in[2];
  const float* pw1    = (const float*)d_in[3];
  const float* wih    = (const float*)d_in[4];
  const float* whh    = (const float*)d_in[5];
  const float* bih    = (const float*)d_in[6];
  const float* bhh    = (const float*)d_in[7];
  const float* ow0    = (const float*)d_in[8];
  const float* ob0    = (const float*)d_in[9];
  const float* ow1    = (const float*)d_in[10];
  const float* ob1    = (const float*)d_in[11];
  const float* ow2    = (const float*)d_in[12];
  const float* ob2    = (const float*)d_in[13];
  const int* ilen     = (const int*)d_in[14];
  const int* mlen     = (const int*)d_in[15];
  float* out = (float*)d_out;

  char* w = (char*)d_ws;
  size_t off = 0;
  auto carve = [&](size_t bytes) -> char* {
    char* p = w + off;
    off = (off + bytes + 255) & ~(size_t)255;
    return p;
  };
  bf16*  ib     = (bf16*)carve(8*128*512 * 2);
  bf16*  ar     = (bf16*)carve(2048*96 * 2);
  bf16*  w0p    = (bf16*)carve(256*96 * 2);
  bf16*  w1b    = (bf16*)carve(256*256 * 2);
  bf16*  wihb   = (bf16*)carve(2048*256 * 2);
  bf16*  whhb   = (bf16*)carve((size_t)2048*512 * 2);
  float* bias2  = (float*)carve(2048 * 4);
  bf16*  ow0Eb  = (bf16*)carve(256*512 * 2);
  bf16*  ow0Mb  = (bf16*)carve(256*512 * 2);
  bf16*  ow1b   = (bf16*)carve(256*256 * 2);
  bf16*  ow2pb  = (bf16*)carve(176*256 * 2);
  float* ob2p   = (float*)carve(176 * 4);
  bf16*  pre1   = (bf16*)carve(2048*256 * 2);
  bf16*  pre2   = (bf16*)carve(2048*256 * 2);
  float* gx     = (float*)carve((size_t)2048*2048 * 4);
  bf16*  baseb  = (bf16*)carve(1024*256 * 2);
  unsigned long long* hg = (unsigned long long*)carve((size_t)256 * 1024 * 8);
  float* hterm  = (float*)carve((size_t)2048*256 * 4);
  float* emb    = (float*)carve((size_t)2048*128 * 4);
  float* tvb    = (float*)carve((size_t)2048*128 * 4);

  k_prep<<<512, 256, 0, stream>>>(inputs, mels, pw0, pw1, wih, whh, bih, bhh, ow0, ow1, ow2, ob2,
                                  ib, ar, w0p, w1b, wihb, whhb, bias2, ow0Eb, ow0Mb, ow1b, ow2pb,
                                  ob2p, hg);
  k_gemm<<<dim3(4, 32), 256, 0, stream>>>(ar, w0p, nullptr, pre1, 2048, 256, 96, 1 | 2);
  k_gemm<<<dim3(4, 32), 256, 0, stream>>>(pre1, w1b, nullptr, pre2, 2048, 256, 256, 1 | 2);
  k_gemm<<<dim3(32, 32), 256, 0, stream>>>(pre2, wihb, bias2, gx, 2048, 2048, 256, 0);
  k_gemm<<<dim3(4, 16), 256, 0, stream>>>(ib, ow0Eb, ob0, baseb, 1024, 256, 512, 2);
  k_lstm<<<16, 512, 0, stream>>>(gx, whhb, hg);
  k_gemm<<<dim3(4, 32), 256, 0, stream>>>((const bf16*)hg, ow0Mb, nullptr, hterm, 2048, 256, 512, 0);
  k_out<<<2048, 256, 0, stream>>>(baseb, hterm, ow1b, ow2pb, ob1, ob2p, mels, ilen, emb, tvb);
  k_hmm<<<8, 64, 0, stream>>>(emb, tvb, ilen, mlen, out);
}